// Round 12
// baseline (133.100 us; speedup 1.0000x reference)
//
#include <hip/hip_runtime.h>

// EfficientAttention (linear attention / Performer-style), MI355X gfx950.
// B=4, S=8192, H=512, NH=8, HD=64, FD=32. All inputs fp32; output fp32.
//
// R12: gemm_qkv reads x DIRECTLY as fp32 (DMA-staged to LDS, converted to
// bf16 on the fragment path via v_cvt_pk_bf16_f32) -> prep's 96MB x round
// trip eliminated (prep is now weights-only). Barrier structure identical to
// the R9/R11-proven loop (global_load_lds + __syncthreads only; the R6
// failure was reg-staged loads on the barrier path — absent here).
// Numerics bit-identical to R11 (cvt_pk is RNE, same as f2bf).
//
//  K0  prep    : WcatT row n=h*128+j (j<32:(Wq@rm)^T, j<64:(Wk@rm)^T, else Wv^T)
//  K1  gemm_qkv: per (h, 128-tok chunk): x(fp32) @ WcatT^T; QF tok-major
//                (elu+1); kv/ksum partials via in-LDS kT/vT + 2nd MFMA stage
//  K2  kv_red  : part[bh][64][2080] -> kvr[bh][2080] fp32   (grid 32x9)
//  K3  mprep_qn: blocks<512: MT tile (b,h,nc); else qn = q'/(q'.ksum+1e-6)
//  K4  gemm_out: out[b] = qn[b] @ M[b]^T + b_out (K=256, B-panel in LDS)

#define DEVFN static __device__ __forceinline__

typedef short short4v __attribute__((ext_vector_type(4)));
typedef short short8 __attribute__((ext_vector_type(8)));
typedef __bf16 bf16x8 __attribute__((ext_vector_type(8)));
typedef float f32x4 __attribute__((ext_vector_type(4)));

DEVFN unsigned short f2bf(float x) {
  unsigned u = __float_as_uint(x);
  u += 0x7FFFu + ((u >> 16) & 1u);   // RNE
  return (unsigned short)(u >> 16);
}
DEVFN float bf2f(unsigned short s) { return __uint_as_float(((unsigned)s) << 16); }

DEVFN unsigned cvtpk(float lo, float hi) {   // 2 f32 -> packed 2 bf16 (RNE)
  unsigned r;
  asm("v_cvt_pk_bf16_f32 %0, %1, %2" : "=v"(r) : "v"(lo), "v"(hi));
  return r;
}
DEVFN short8 cvt8(f32x4 a, f32x4 b) {        // 8 f32 -> short8 of bf16
  union { unsigned u[4]; short8 s; } r;
  r.u[0] = cvtpk(a[0], a[1]); r.u[1] = cvtpk(a[2], a[3]);
  r.u[2] = cvtpk(b[0], b[1]); r.u[3] = cvtpk(b[2], b[3]);
  return r.s;
}

DEVFN f32x4 mfma16(short8 a, short8 b, f32x4 c) {
  return __builtin_amdgcn_mfma_f32_16x16x32_bf16(
      __builtin_bit_cast(bf16x8, a), __builtin_bit_cast(bf16x8, b), c, 0, 0, 0);
}

DEVFN void gload16(const void* g, void* l) {
  __builtin_amdgcn_global_load_lds((__attribute__((address_space(1))) unsigned*)g,
                                   (__attribute__((address_space(3))) unsigned*)l,
                                   16, 0, 0);
}

// ---------------- K0: weight prep (weights only) ----------------
__global__ __launch_bounds__(256) void prep(const float* __restrict__ Wqkv,
                                            const float* __restrict__ rm,
                                            unsigned short* __restrict__ WcatT) {
  const int t = threadIdx.x;
  const int n = blockIdx.x;                 // 0..1023
  const int h = n >> 7, j = n & 127;
  if (j < 64) {                             // q'/k' feature rows
    const int d = j & 31;
    const int colbase = (j >= 32 ? 512 : 0) + h * 64;
    for (int k = t; k < 512; k += 256) {
      float s = 0.f;
      const float* wrow = Wqkv + (size_t)k * 1536 + colbase;
      #pragma unroll 8
      for (int e = 0; e < 64; ++e) s += wrow[e] * rm[e * 32 + d];
      WcatT[(size_t)n * 512 + k] = f2bf(s);
    }
  } else {                                  // v rows
    const int f = j - 64;
    for (int k = t; k < 512; k += 256)
      WcatT[(size_t)n * 512 + k] = f2bf(Wqkv[(size_t)k * 1536 + 1024 + h * 64 + f]);
  }
}

// ---------------- K1: head-tiled qkv GEMM (fp32 A) + fused kv ----------------
// grid 2048. Block = (head h, chunk of 128 tokens).
__global__ __launch_bounds__(256) void gemm_qkv(
    const float* __restrict__ X,             // 32768 x 512 fp32
    const unsigned short* __restrict__ BT,   // 1024 x 512 bf16 (head layout)
    unsigned short* __restrict__ OQ,         // QF 32768 x 256
    float* __restrict__ part) {              // [bh][64][2080]
  // A bufs (fp32): [0,16K) [16K,32K). B bufs (bf16): [32K,40K) [40K,48K).
  // kv stage (after final K-loop barrier) reuses [0, 26880).
  __shared__ __attribute__((aligned(16))) unsigned char lds[49152];
  const int t = threadIdx.x;
  const int lane = t & 63, w = t >> 6;
  const int wr = w >> 1, wc = w & 1;
  const int col = lane & 15, kg = lane >> 4;

  const int l = blockIdx.x;
  const int xcd = l & 7, j = l >> 3;          // j: 0..255
  const int chunk = xcd * 32 + (j >> 3);      // 0..255 (128 tokens each)
  const int h = j & 7;
  const int bh = (chunk >> 6) * 8 + h;

  const long m0 = (long)chunk * 128;
  // A (fp32): wave w stages rows [w*32, w*32+32); gload i covers 8 rows.
  const float* gxa = X + (m0 + w * 32 + (lane >> 3)) * 512 + (lane & 7) * 4;
  const unsigned short* gb = BT + ((size_t)h * 128 + (t >> 2)) * 512 + (t & 3) * 8;

  f32x4 acc[4][4] = {};

#define STAGE(buf, kt)                                      \
  {                                                         \
    const int ko_ = (kt) * 32;                              \
    unsigned char* la_ = lds + (buf) * 16384 + w * 4096;    \
    unsigned char* lb_ = lds + 32768 + (buf) * 8192 + w * 1024; \
    gload16(gxa + ko_, la_);                                \
    gload16(gxa + 8 * 512 + ko_, la_ + 1024);               \
    gload16(gxa + 16 * 512 + ko_, la_ + 2048);              \
    gload16(gxa + 24 * 512 + ko_, la_ + 3072);              \
    gload16(gb + ko_, lb_);                                 \
    gload16(gb + 64 * 512 + ko_, lb_ + 4096);               \
  }
  STAGE(0, 0);
  __syncthreads();                 // drains vmcnt(0): tile 0 resident
  int buf = 0;
  for (int kt = 0; kt < 16; ++kt) {
    if (kt + 1 < 16) STAGE(buf ^ 1, kt + 1);
    const float* Af = (const float*)(lds + buf * 16384);
    const unsigned short* Bs_ = (const unsigned short*)(lds + 32768 + buf * 8192);
    short8 af[4], bfr[4];
    #pragma unroll
    for (int mi = 0; mi < 4; ++mi) {
      const int row = wr * 64 + mi * 16 + col;
      f32x4 x0 = *(const f32x4*)(Af + row * 32 + kg * 8);
      f32x4 x1 = *(const f32x4*)(Af + row * 32 + kg * 8 + 4);
      af[mi] = cvt8(x0, x1);
    }
    #pragma unroll
    for (int ni = 0; ni < 4; ++ni)
      bfr[ni] = *(const short8*)&Bs_[(wc * 64 + ni * 16 + col) * 32 + kg * 8];
    #pragma unroll
    for (int mi = 0; mi < 4; ++mi)
      #pragma unroll
      for (int ni = 0; ni < 4; ++ni)
        acc[mi][ni] = mfma16(af[mi], bfr[ni], acc[mi][ni]);
    __syncthreads();
    buf ^= 1;
  }
#undef STAGE

  unsigned short* kT = (unsigned short*)lds;          // 32 x 140
  unsigned short* vT = (unsigned short*)lds + 4480;   // 64 x 140

  if (wc == 0) {
    #pragma unroll
    for (int ni = 0; ni < 2; ++ni) {
      const int c = h * 32 + ni * 16 + col;
      #pragma unroll
      for (int mi = 0; mi < 4; ++mi)
        #pragma unroll
        for (int r = 0; r < 4; ++r) {
          const long row = m0 + wr * 64 + mi * 16 + kg * 4 + r;
          float v = acc[mi][ni][r];
          v = v > 0.f ? v + 1.f : __expf(v);
          OQ[(size_t)row * 256 + c] = f2bf(v);
        }
    }
    #pragma unroll
    for (int ni = 0; ni < 2; ++ni) {
      const int d = ni * 16 + col;
      #pragma unroll
      for (int mi = 0; mi < 4; ++mi) {
        const int tt0 = wr * 64 + mi * 16 + kg * 4;
        short4v pk;
        #pragma unroll
        for (int r = 0; r < 4; ++r) {
          float v = acc[mi][2 + ni][r];
          v = v > 0.f ? v + 1.f : __expf(v);
          pk[r] = (short)f2bf(v);
        }
        *(short4v*)&kT[d * 140 + tt0] = pk;
      }
    }
  } else {
    #pragma unroll
    for (int ni = 0; ni < 4; ++ni) {
      const int f = ni * 16 + col;
      #pragma unroll
      for (int mi = 0; mi < 4; ++mi) {
        const int tt0 = wr * 64 + mi * 16 + kg * 4;
        short4v pk;
        #pragma unroll
        for (int r = 0; r < 4; ++r) pk[r] = (short)f2bf(acc[mi][ni][r]);
        *(short4v*)&vT[f * 140 + tt0] = pk;
      }
    }
  }
  __syncthreads();   // kT/vT visible to all waves

  f32x4 acc_kv[2] = {};
  f32x4 acc_ks[2] = {};
  short8 ones;
  #pragma unroll
  for (int i = 0; i < 8; ++i) ones[i] = (short)0x3F80;   // bf16 1.0
  #pragma unroll
  for (int ks = 0; ks < 4; ++ks) {
    short8 bv = *(const short8*)&vT[(w * 16 + col) * 140 + ks * 32 + kg * 8];
    short8 a0 = *(const short8*)&kT[col * 140 + ks * 32 + kg * 8];
    short8 a1 = *(const short8*)&kT[(16 + col) * 140 + ks * 32 + kg * 8];
    acc_kv[0] = mfma16(a0, bv, acc_kv[0]);
    acc_kv[1] = mfma16(a1, bv, acc_kv[1]);
    if (w == 0) {
      acc_ks[0] = mfma16(a0, ones, acc_ks[0]);
      acc_ks[1] = mfma16(a1, ones, acc_ks[1]);
    }
  }

  float* p = part + ((size_t)bh * 64 + (chunk & 63)) * 2080;
  #pragma unroll
  for (int df = 0; df < 2; ++df)
    #pragma unroll
    for (int r = 0; r < 4; ++r) {
      const int d = df * 16 + kg * 4 + r;
      p[d * 64 + w * 16 + col] = acc_kv[df][r];
    }
  if (w == 0 && col == 0) {
    #pragma unroll
    for (int df = 0; df < 2; ++df)
      #pragma unroll
      for (int r = 0; r < 4; ++r)
        p[2048 + df * 16 + kg * 4 + r] = acc_ks[df][r];
  }
}

// ---------------- K2: reduce partials (grid 32 x 9) ----------------
__global__ __launch_bounds__(256) void kv_reduce(const float* __restrict__ part,
                                                 float* __restrict__ kvr) {
  const int bh = blockIdx.x, t = threadIdx.x;
  const int idx = blockIdx.y * 256 + t;
  if (idx >= 2080) return;
  float s = 0.f;
  #pragma unroll 8
  for (int c = 0; c < 64; ++c) s += part[((size_t)bh * 64 + c) * 2080 + idx];
  kvr[(size_t)bh * 2080 + idx] = s;
}

// ---------------- K3: merged mprep (blocks<512, LDS-tiled) + qn ----------
__global__ __launch_bounds__(256) void mprep_qn(const float* __restrict__ kvr,
                                                const float* __restrict__ Wout,
                                                const unsigned short* __restrict__ QF,
                                                unsigned short* __restrict__ MT,
                                                unsigned short* __restrict__ QN) {
  const int t = threadIdx.x;
  if (blockIdx.x < 512) {
    // MT[b][n0+n][h*32+d] = sum_f kv[b,h,d,f] * Wout[h*64+f][n0+n]
    __shared__ float Wt[64][33];   // [f][n], padded
    __shared__ float kvt[32][64];  // [d][f]
    const int bx = blockIdx.x;
    const int b = bx >> 7, rem = bx & 127;
    const int h = rem >> 4, n0 = (rem & 15) * 32;
    {
      const int f0 = t >> 5, c = t & 31;      // 8 f-rows per pass
      #pragma unroll
      for (int i = 0; i < 8; ++i)
        Wt[f0 + i * 8][c] = Wout[(size_t)(h * 64 + f0 + i * 8) * 512 + n0 + c];
      const float* kvp = kvr + (size_t)(b * 8 + h) * 2080;
      #pragma unroll
      for (int i = 0; i < 2; ++i) {           // 2048 floats: 2 x f32x4/thread
        const int off = t * 4 + i * 1024;
        f32x4 kk = *(const f32x4*)(kvp + off);
        *(f32x4*)&kvt[off >> 6][off & 63] = kk;
      }
    }
    __syncthreads();
    const int n = t & 31, dg = (t >> 5) * 4;  // 4 consecutive d per thread
    float s0 = 0.f, s1 = 0.f, s2 = 0.f, s3 = 0.f;
    #pragma unroll 8
    for (int f = 0; f < 64; ++f) {
      const float wv = Wt[f][n];
      s0 += kvt[dg + 0][f] * wv;
      s1 += kvt[dg + 1][f] * wv;
      s2 += kvt[dg + 2][f] * wv;
      s3 += kvt[dg + 3][f] * wv;
    }
    short4v o;
    o[0] = (short)f2bf(s0); o[1] = (short)f2bf(s1);
    o[2] = (short)f2bf(s2); o[3] = (short)f2bf(s3);
    *(short4v*)&MT[((size_t)b * 512 + n0 + n) * 256 + h * 32 + dg] = o;
  } else {
    __shared__ float ks[256];
    const int bq = blockIdx.x - 512;
    const size_t tid = (size_t)bq * 256 + t;
    const int tok0 = bq * 32;
    const int b = tok0 >> 13;
    ks[t] = kvr[(size_t)(b * 8 + (t >> 5)) * 2080 + 2048 + (t & 31)];
    __syncthreads();
    const int tok = (int)(tid >> 3), h = (int)(tid & 7);
    const short8* q = (const short8*)(QF + (size_t)tok * 256 + h * 32);
    short8 v[4];
    #pragma unroll
    for (int i = 0; i < 4; ++i) v[i] = q[i];
    float den = 1e-6f;
    #pragma unroll
    for (int i = 0; i < 4; ++i)
      #pragma unroll
      for (int j = 0; j < 8; ++j)
        den += bf2f((unsigned short)v[i][j]) * ks[h * 32 + i * 8 + j];
    const float inv = 1.f / den;
    short8* o = (short8*)(QN + (size_t)tok * 256 + h * 32);
    #pragma unroll
    for (int i = 0; i < 4; ++i) {
      short8 ov;
      #pragma unroll
      for (int j = 0; j < 8; ++j)
        ov[j] = (short)f2bf(bf2f((unsigned short)v[i][j]) * inv);
      o[i] = ov;
    }
  }
}

// ---------------- K4: out = qn @ M^T + bias (K=256) ----------------
__global__ __launch_bounds__(256) void gemm_out(
    const unsigned short* __restrict__ QN,   // 32768 x 256
    const unsigned short* __restrict__ MT,   // [4][512][256]
    const float* __restrict__ bias,
    float* __restrict__ OC) {
  __shared__ __attribute__((aligned(16))) unsigned short Bls[32768];  // 64 KB
  const int t = threadIdx.x;
  const int lane = t & 63, w = t >> 6;
  const int wr = w >> 1, wc = w & 1;
  const int col = lane & 15, kg = lane >> 4;

  const int nx = gridDim.x;
  int wg = blockIdx.y * nx + blockIdx.x;
  const int cpx = (nx * (int)gridDim.y) >> 3;
  wg = (wg & 7) * cpx + (wg >> 3);
  const int bx = wg % nx, by = wg / nx;
  const long m0 = (long)by * 128;
  const long n0 = (long)bx * 128;
  const long b = m0 >> 13;
  const unsigned short* MTb = MT + b * 512 * 256;

  #pragma unroll
  for (int i = 0; i < 16; ++i) {
    const int u = i * 256 + t;
    const int slab = u >> 9, row = (u >> 2) & 127, ch = u & 3;
    gload16(MTb + ((size_t)(n0 + row)) * 256 + slab * 32 + ch * 8,
            Bls + ((size_t)i * 256 + w * 64) * 8);
  }
  __syncthreads();

  f32x4 acc[4][4] = {};
  #pragma unroll 2
  for (int kt = 0; kt < 8; ++kt) {
    short8 af[4], bfr[4];
    #pragma unroll
    for (int mi = 0; mi < 4; ++mi)
      af[mi] = *(const short8*)&QN[(m0 + wr * 64 + mi * 16 + col) * 256 +
                                   kt * 32 + kg * 8];
    #pragma unroll
    for (int ni = 0; ni < 4; ++ni)
      bfr[ni] = *(const short8*)&Bls[kt * 4096 +
                                     (wc * 64 + ni * 16 + col) * 32 + kg * 8];
    #pragma unroll
    for (int mi = 0; mi < 4; ++mi)
      #pragma unroll
      for (int ni = 0; ni < 4; ++ni)
        acc[mi][ni] = mfma16(af[mi], bfr[ni], acc[mi][ni]);
  }

  const int rowb = (int)m0 + wr * 64;
  const int colb = (int)n0 + wc * 64;
  #pragma unroll
  for (int ni = 0; ni < 4; ++ni) {
    const int c = colb + ni * 16 + col;
    const float bb = bias[c];
    #pragma unroll
    for (int mi = 0; mi < 4; ++mi) {
      #pragma unroll
      for (int r = 0; r < 4; ++r) {
        const int row = rowb + mi * 16 + kg * 4 + r;
        OC[(size_t)row * 512 + c] = acc[mi][ni][r] + bb;
      }
    }
  }
}

extern "C" void kernel_launch(void* const* d_in, const int* in_sizes, int n_in,
                              void* d_out, int out_size, void* d_ws, size_t ws_size,
                              hipStream_t stream) {
  const float* x    = (const float*)d_in[0];
  const float* Wqkv = (const float*)d_in[1];
  const float* rm   = (const float*)d_in[2];
  const float* Wout = (const float*)d_in[3];
  const float* bout = (const float*)d_in[4];
  float* out = (float*)d_out;

  char* ws = (char*)d_ws;
  // Lifetimes: WcatT [prep .. gemm_qkv); QF [gemm_qkv .. mprep_qn);
  // part [gemm_qkv .. kv_reduce); kvr [kv_reduce .. mprep_qn);
  // QN/MT [mprep_qn .. gemm_out). All regions disjoint.
  unsigned short* QN    = (unsigned short*)(ws);              // [0, 16,777,216)
  unsigned short* MT    = (unsigned short*)(ws + 16777216);   // [.., 17,825,792)
  unsigned short* WcatT = (unsigned short*)(ws + 33554432);   // [.., 34,603,008)
  unsigned short* QF    = (unsigned short*)(ws + 34603008);   // [.., 51,380,224)
  float* part           = (float*)(ws + 51380224);            // [.., 68,419,584)
  float* kvr            = (float*)(ws + 68419584);            // [.., 68,685,824)

  if (ws_size < 68685824u) return;

  prep<<<dim3(1024), dim3(256), 0, stream>>>(Wqkv, rm, WcatT);
  gemm_qkv<<<dim3(2048), dim3(256), 0, stream>>>(x, WcatT, QF, part);
  kv_reduce<<<dim3(32, 9), dim3(256), 0, stream>>>(part, kvr);
  mprep_qn<<<dim3(1536), dim3(256), 0, stream>>>(kvr, Wout, QF, MT, QN);
  gemm_out<<<dim3(4, 256), dim3(256), 0, stream>>>(QN, MT, bout, out);
}

// Round 13
// 131.971 us; speedup vs baseline: 1.0086x; 1.0086x over previous
//
#include <hip/hip_runtime.h>

// EfficientAttention (linear attention / Performer-style), MI355X gfx950.
// B=4, S=8192, H=512, NH=8, HD=64, FD=32. All inputs fp32; output fp32.
//
// R13 = R12 + chunk-XOR swizzle on the fp32 A tile (rule #21: linear LDS dest
// via global_load_lds + pre-swizzled GLOBAL source + same XOR on the LDS
// read). R12's 16-way bank conflict on the A fragment read (row stride 128B =
// bank wrap) caused SQ_LDS_BANK_CONFLICT 4.2M->14.7M and gemm_qkv 57->85us.
// Swizzle: lane (r=lane>>3, c=lane&7) stages global chunk c^r of row r;
// read fetches LDS chunk (2kg)^(row&7) / (2kg+1)^(row&7). 2-way/quarter-wave
// -> free. Numerics bit-identical (same values, same order).
//
//  K0  prep    : WcatT row n=h*128+j (j<32:(Wq@rm)^T, j<64:(Wk@rm)^T, else Wv^T)
//  K1  gemm_qkv: per (h, 128-tok chunk): x(fp32) @ WcatT^T; QF tok-major
//                (elu+1); kv/ksum partials via in-LDS kT/vT + 2nd MFMA stage
//  K2  kv_red  : part[bh][64][2080] -> kvr[bh][2080] fp32   (grid 32x9)
//  K3  mprep_qn: blocks<512: MT tile (b,h,nc); else qn = q'/(q'.ksum+1e-6)
//  K4  gemm_out: out[b] = qn[b] @ M[b]^T + b_out (K=256, B-panel in LDS)

#define DEVFN static __device__ __forceinline__

typedef short short4v __attribute__((ext_vector_type(4)));
typedef short short8 __attribute__((ext_vector_type(8)));
typedef __bf16 bf16x8 __attribute__((ext_vector_type(8)));
typedef float f32x4 __attribute__((ext_vector_type(4)));

DEVFN unsigned short f2bf(float x) {
  unsigned u = __float_as_uint(x);
  u += 0x7FFFu + ((u >> 16) & 1u);   // RNE
  return (unsigned short)(u >> 16);
}
DEVFN float bf2f(unsigned short s) { return __uint_as_float(((unsigned)s) << 16); }

DEVFN unsigned cvtpk(float lo, float hi) {   // 2 f32 -> packed 2 bf16 (RNE)
  unsigned r;
  asm("v_cvt_pk_bf16_f32 %0, %1, %2" : "=v"(r) : "v"(lo), "v"(hi));
  return r;
}
DEVFN short8 cvt8(f32x4 a, f32x4 b) {        // 8 f32 -> short8 of bf16
  union { unsigned u[4]; short8 s; } r;
  r.u[0] = cvtpk(a[0], a[1]); r.u[1] = cvtpk(a[2], a[3]);
  r.u[2] = cvtpk(b[0], b[1]); r.u[3] = cvtpk(b[2], b[3]);
  return r.s;
}

DEVFN f32x4 mfma16(short8 a, short8 b, f32x4 c) {
  return __builtin_amdgcn_mfma_f32_16x16x32_bf16(
      __builtin_bit_cast(bf16x8, a), __builtin_bit_cast(bf16x8, b), c, 0, 0, 0);
}

DEVFN void gload16(const void* g, void* l) {
  __builtin_amdgcn_global_load_lds((__attribute__((address_space(1))) unsigned*)g,
                                   (__attribute__((address_space(3))) unsigned*)l,
                                   16, 0, 0);
}

// ---------------- K0: weight prep (weights only) ----------------
__global__ __launch_bounds__(256) void prep(const float* __restrict__ Wqkv,
                                            const float* __restrict__ rm,
                                            unsigned short* __restrict__ WcatT) {
  const int t = threadIdx.x;
  const int n = blockIdx.x;                 // 0..1023
  const int h = n >> 7, j = n & 127;
  if (j < 64) {                             // q'/k' feature rows
    const int d = j & 31;
    const int colbase = (j >= 32 ? 512 : 0) + h * 64;
    for (int k = t; k < 512; k += 256) {
      float s = 0.f;
      const float* wrow = Wqkv + (size_t)k * 1536 + colbase;
      #pragma unroll 8
      for (int e = 0; e < 64; ++e) s += wrow[e] * rm[e * 32 + d];
      WcatT[(size_t)n * 512 + k] = f2bf(s);
    }
  } else {                                  // v rows
    const int f = j - 64;
    for (int k = t; k < 512; k += 256)
      WcatT[(size_t)n * 512 + k] = f2bf(Wqkv[(size_t)k * 1536 + 1024 + h * 64 + f]);
  }
}

// ---------------- K1: head-tiled qkv GEMM (fp32 A, swizzled) + fused kv ------
// grid 2048. Block = (head h, chunk of 128 tokens).
__global__ __launch_bounds__(256) void gemm_qkv(
    const float* __restrict__ X,             // 32768 x 512 fp32
    const unsigned short* __restrict__ BT,   // 1024 x 512 bf16 (head layout)
    unsigned short* __restrict__ OQ,         // QF 32768 x 256
    float* __restrict__ part) {              // [bh][64][2080]
  // A bufs (fp32): [0,16K) [16K,32K). B bufs (bf16): [32K,40K) [40K,48K).
  // kv stage (after final K-loop barrier) reuses [0, 26880).
  __shared__ __attribute__((aligned(16))) unsigned char lds[49152];
  const int t = threadIdx.x;
  const int lane = t & 63, w = t >> 6;
  const int wr = w >> 1, wc = w & 1;
  const int col = lane & 15, kg = lane >> 4;

  const int l = blockIdx.x;
  const int xcd = l & 7, j = l >> 3;          // j: 0..255
  const int chunk = xcd * 32 + (j >> 3);      // 0..255 (128 tokens each)
  const int h = j & 7;
  const int bh = (chunk >> 6) * 8 + h;

  const long m0 = (long)chunk * 128;
  // A (fp32): wave w stages rows [w*32, w*32+32); each gload covers 8 rows.
  // Chunk-XOR: lane (r=lane>>3, c=lane&7) fetches global 16B-chunk c^r of its
  // row; LDS dest stays linear (gload_lds). Read applies the same XOR.
  const int csw = ((lane & 7) ^ (lane >> 3)) * 4;   // floats
  const float* gxa = X + (m0 + w * 32 + (lane >> 3)) * 512 + csw;
  const unsigned short* gb = BT + ((size_t)h * 128 + (t >> 2)) * 512 + (t & 3) * 8;

  f32x4 acc[4][4] = {};

#define STAGE(buf, kt)                                      \
  {                                                         \
    const int ko_ = (kt) * 32;                              \
    unsigned char* la_ = lds + (buf) * 16384 + w * 4096;    \
    unsigned char* lb_ = lds + 32768 + (buf) * 8192 + w * 1024; \
    gload16(gxa + ko_, la_);                                \
    gload16(gxa + 8 * 512 + ko_, la_ + 1024);               \
    gload16(gxa + 16 * 512 + ko_, la_ + 2048);              \
    gload16(gxa + 24 * 512 + ko_, la_ + 3072);              \
    gload16(gb + ko_, lb_);                                 \
    gload16(gb + 64 * 512 + ko_, lb_ + 4096);               \
  }
  STAGE(0, 0);
  __syncthreads();                 // drains vmcnt(0): tile 0 resident
  int buf = 0;
  for (int kt = 0; kt < 16; ++kt) {
    if (kt + 1 < 16) STAGE(buf ^ 1, kt + 1);
    const float* Af = (const float*)(lds + buf * 16384);
    const unsigned short* Bs_ = (const unsigned short*)(lds + 32768 + buf * 8192);
    short8 af[4], bfr[4];
    #pragma unroll
    for (int mi = 0; mi < 4; ++mi) {
      const int row = wr * 64 + mi * 16 + col;
      const int r7 = row & 7;
      f32x4 x0 = *(const f32x4*)(Af + row * 32 + ((((kg << 1)    ) ^ r7) << 2));
      f32x4 x1 = *(const f32x4*)(Af + row * 32 + ((((kg << 1) | 1) ^ r7) << 2));
      af[mi] = cvt8(x0, x1);
    }
    #pragma unroll
    for (int ni = 0; ni < 4; ++ni)
      bfr[ni] = *(const short8*)&Bs_[(wc * 64 + ni * 16 + col) * 32 + kg * 8];
    #pragma unroll
    for (int mi = 0; mi < 4; ++mi)
      #pragma unroll
      for (int ni = 0; ni < 4; ++ni)
        acc[mi][ni] = mfma16(af[mi], bfr[ni], acc[mi][ni]);
    __syncthreads();
    buf ^= 1;
  }
#undef STAGE

  unsigned short* kT = (unsigned short*)lds;          // 32 x 140
  unsigned short* vT = (unsigned short*)lds + 4480;   // 64 x 140

  if (wc == 0) {
    #pragma unroll
    for (int ni = 0; ni < 2; ++ni) {
      const int c = h * 32 + ni * 16 + col;
      #pragma unroll
      for (int mi = 0; mi < 4; ++mi)
        #pragma unroll
        for (int r = 0; r < 4; ++r) {
          const long row = m0 + wr * 64 + mi * 16 + kg * 4 + r;
          float v = acc[mi][ni][r];
          v = v > 0.f ? v + 1.f : __expf(v);
          OQ[(size_t)row * 256 + c] = f2bf(v);
        }
    }
    #pragma unroll
    for (int ni = 0; ni < 2; ++ni) {
      const int d = ni * 16 + col;
      #pragma unroll
      for (int mi = 0; mi < 4; ++mi) {
        const int tt0 = wr * 64 + mi * 16 + kg * 4;
        short4v pk;
        #pragma unroll
        for (int r = 0; r < 4; ++r) {
          float v = acc[mi][2 + ni][r];
          v = v > 0.f ? v + 1.f : __expf(v);
          pk[r] = (short)f2bf(v);
        }
        *(short4v*)&kT[d * 140 + tt0] = pk;
      }
    }
  } else {
    #pragma unroll
    for (int ni = 0; ni < 4; ++ni) {
      const int f = ni * 16 + col;
      #pragma unroll
      for (int mi = 0; mi < 4; ++mi) {
        const int tt0 = wr * 64 + mi * 16 + kg * 4;
        short4v pk;
        #pragma unroll
        for (int r = 0; r < 4; ++r) pk[r] = (short)f2bf(acc[mi][ni][r]);
        *(short4v*)&vT[f * 140 + tt0] = pk;
      }
    }
  }
  __syncthreads();   // kT/vT visible to all waves

  f32x4 acc_kv[2] = {};
  f32x4 acc_ks[2] = {};
  short8 ones;
  #pragma unroll
  for (int i = 0; i < 8; ++i) ones[i] = (short)0x3F80;   // bf16 1.0
  #pragma unroll
  for (int ks = 0; ks < 4; ++ks) {
    short8 bv = *(const short8*)&vT[(w * 16 + col) * 140 + ks * 32 + kg * 8];
    short8 a0 = *(const short8*)&kT[col * 140 + ks * 32 + kg * 8];
    short8 a1 = *(const short8*)&kT[(16 + col) * 140 + ks * 32 + kg * 8];
    acc_kv[0] = mfma16(a0, bv, acc_kv[0]);
    acc_kv[1] = mfma16(a1, bv, acc_kv[1]);
    if (w == 0) {
      acc_ks[0] = mfma16(a0, ones, acc_ks[0]);
      acc_ks[1] = mfma16(a1, ones, acc_ks[1]);
    }
  }

  float* p = part + ((size_t)bh * 64 + (chunk & 63)) * 2080;
  #pragma unroll
  for (int df = 0; df < 2; ++df)
    #pragma unroll
    for (int r = 0; r < 4; ++r) {
      const int d = df * 16 + kg * 4 + r;
      p[d * 64 + w * 16 + col] = acc_kv[df][r];
    }
  if (w == 0 && col == 0) {
    #pragma unroll
    for (int df = 0; df < 2; ++df)
      #pragma unroll
      for (int r = 0; r < 4; ++r)
        p[2048 + df * 16 + kg * 4 + r] = acc_ks[df][r];
  }
}

// ---------------- K2: reduce partials (grid 32 x 9) ----------------
__global__ __launch_bounds__(256) void kv_reduce(const float* __restrict__ part,
                                                 float* __restrict__ kvr) {
  const int bh = blockIdx.x, t = threadIdx.x;
  const int idx = blockIdx.y * 256 + t;
  if (idx >= 2080) return;
  float s = 0.f;
  #pragma unroll 8
  for (int c = 0; c < 64; ++c) s += part[((size_t)bh * 64 + c) * 2080 + idx];
  kvr[(size_t)bh * 2080 + idx] = s;
}

// ---------------- K3: merged mprep (blocks<512, LDS-tiled) + qn ----------
__global__ __launch_bounds__(256) void mprep_qn(const float* __restrict__ kvr,
                                                const float* __restrict__ Wout,
                                                const unsigned short* __restrict__ QF,
                                                unsigned short* __restrict__ MT,
                                                unsigned short* __restrict__ QN) {
  const int t = threadIdx.x;
  if (blockIdx.x < 512) {
    // MT[b][n0+n][h*32+d] = sum_f kv[b,h,d,f] * Wout[h*64+f][n0+n]
    __shared__ float Wt[64][33];   // [f][n], padded
    __shared__ float kvt[32][64];  // [d][f]
    const int bx = blockIdx.x;
    const int b = bx >> 7, rem = bx & 127;
    const int h = rem >> 4, n0 = (rem & 15) * 32;
    {
      const int f0 = t >> 5, c = t & 31;      // 8 f-rows per pass
      #pragma unroll
      for (int i = 0; i < 8; ++i)
        Wt[f0 + i * 8][c] = Wout[(size_t)(h * 64 + f0 + i * 8) * 512 + n0 + c];
      const float* kvp = kvr + (size_t)(b * 8 + h) * 2080;
      #pragma unroll
      for (int i = 0; i < 2; ++i) {           // 2048 floats: 2 x f32x4/thread
        const int off = t * 4 + i * 1024;
        f32x4 kk = *(const f32x4*)(kvp + off);
        *(f32x4*)&kvt[off >> 6][off & 63] = kk;
      }
    }
    __syncthreads();
    const int n = t & 31, dg = (t >> 5) * 4;  // 4 consecutive d per thread
    float s0 = 0.f, s1 = 0.f, s2 = 0.f, s3 = 0.f;
    #pragma unroll 8
    for (int f = 0; f < 64; ++f) {
      const float wv = Wt[f][n];
      s0 += kvt[dg + 0][f] * wv;
      s1 += kvt[dg + 1][f] * wv;
      s2 += kvt[dg + 2][f] * wv;
      s3 += kvt[dg + 3][f] * wv;
    }
    short4v o;
    o[0] = (short)f2bf(s0); o[1] = (short)f2bf(s1);
    o[2] = (short)f2bf(s2); o[3] = (short)f2bf(s3);
    *(short4v*)&MT[((size_t)b * 512 + n0 + n) * 256 + h * 32 + dg] = o;
  } else {
    __shared__ float ks[256];
    const int bq = blockIdx.x - 512;
    const size_t tid = (size_t)bq * 256 + t;
    const int tok0 = bq * 32;
    const int b = tok0 >> 13;
    ks[t] = kvr[(size_t)(b * 8 + (t >> 5)) * 2080 + 2048 + (t & 31)];
    __syncthreads();
    const int tok = (int)(tid >> 3), h = (int)(tid & 7);
    const short8* q = (const short8*)(QF + (size_t)tok * 256 + h * 32);
    short8 v[4];
    #pragma unroll
    for (int i = 0; i < 4; ++i) v[i] = q[i];
    float den = 1e-6f;
    #pragma unroll
    for (int i = 0; i < 4; ++i)
      #pragma unroll
      for (int j = 0; j < 8; ++j)
        den += bf2f((unsigned short)v[i][j]) * ks[h * 32 + i * 8 + j];
    const float inv = 1.f / den;
    short8* o = (short8*)(QN + (size_t)tok * 256 + h * 32);
    #pragma unroll
    for (int i = 0; i < 4; ++i) {
      short8 ov;
      #pragma unroll
      for (int j = 0; j < 8; ++j)
        ov[j] = (short)f2bf(bf2f((unsigned short)v[i][j]) * inv);
      o[i] = ov;
    }
  }
}

// ---------------- K4: out = qn @ M^T + bias (K=256) ----------------
__global__ __launch_bounds__(256) void gemm_out(
    const unsigned short* __restrict__ QN,   // 32768 x 256
    const unsigned short* __restrict__ MT,   // [4][512][256]
    const float* __restrict__ bias,
    float* __restrict__ OC) {
  __shared__ __attribute__((aligned(16))) unsigned short Bls[32768];  // 64 KB
  const int t = threadIdx.x;
  const int lane = t & 63, w = t >> 6;
  const int wr = w >> 1, wc = w & 1;
  const int col = lane & 15, kg = lane >> 4;

  const int nx = gridDim.x;
  int wg = blockIdx.y * nx + blockIdx.x;
  const int cpx = (nx * (int)gridDim.y) >> 3;
  wg = (wg & 7) * cpx + (wg >> 3);
  const int bx = wg % nx, by = wg / nx;
  const long m0 = (long)by * 128;
  const long n0 = (long)bx * 128;
  const long b = m0 >> 13;
  const unsigned short* MTb = MT + b * 512 * 256;

  #pragma unroll
  for (int i = 0; i < 16; ++i) {
    const int u = i * 256 + t;
    const int slab = u >> 9, row = (u >> 2) & 127, ch = u & 3;
    gload16(MTb + ((size_t)(n0 + row)) * 256 + slab * 32 + ch * 8,
            Bls + ((size_t)i * 256 + w * 64) * 8);
  }
  __syncthreads();

  f32x4 acc[4][4] = {};
  #pragma unroll 2
  for (int kt = 0; kt < 8; ++kt) {
    short8 af[4], bfr[4];
    #pragma unroll
    for (int mi = 0; mi < 4; ++mi)
      af[mi] = *(const short8*)&QN[(m0 + wr * 64 + mi * 16 + col) * 256 +
                                   kt * 32 + kg * 8];
    #pragma unroll
    for (int ni = 0; ni < 4; ++ni)
      bfr[ni] = *(const short8*)&Bls[kt * 4096 +
                                     (wc * 64 + ni * 16 + col) * 32 + kg * 8];
    #pragma unroll
    for (int mi = 0; mi < 4; ++mi)
      #pragma unroll
      for (int ni = 0; ni < 4; ++ni)
        acc[mi][ni] = mfma16(af[mi], bfr[ni], acc[mi][ni]);
  }

  const int rowb = (int)m0 + wr * 64;
  const int colb = (int)n0 + wc * 64;
  #pragma unroll
  for (int ni = 0; ni < 4; ++ni) {
    const int c = colb + ni * 16 + col;
    const float bb = bias[c];
    #pragma unroll
    for (int mi = 0; mi < 4; ++mi) {
      #pragma unroll
      for (int r = 0; r < 4; ++r) {
        const int row = rowb + mi * 16 + kg * 4 + r;
        OC[(size_t)row * 512 + c] = acc[mi][ni][r] + bb;
      }
    }
  }
}

extern "C" void kernel_launch(void* const* d_in, const int* in_sizes, int n_in,
                              void* d_out, int out_size, void* d_ws, size_t ws_size,
                              hipStream_t stream) {
  const float* x    = (const float*)d_in[0];
  const float* Wqkv = (const float*)d_in[1];
  const float* rm   = (const float*)d_in[2];
  const float* Wout = (const float*)d_in[3];
  const float* bout = (const float*)d_in[4];
  float* out = (float*)d_out;

  char* ws = (char*)d_ws;
  unsigned short* QN    = (unsigned short*)(ws);              // [0, 16,777,216)
  unsigned short* MT    = (unsigned short*)(ws + 16777216);   // [.., 17,825,792)
  unsigned short* WcatT = (unsigned short*)(ws + 33554432);   // [.., 34,603,008)
  unsigned short* QF    = (unsigned short*)(ws + 34603008);   // [.., 51,380,224)
  float* part           = (float*)(ws + 51380224);            // [.., 68,419,584)
  float* kvr            = (float*)(ws + 68419584);            // [.., 68,685,824)

  if (ws_size < 68685824u) return;

  prep<<<dim3(1024), dim3(256), 0, stream>>>(Wqkv, rm, WcatT);
  gemm_qkv<<<dim3(2048), dim3(256), 0, stream>>>(x, WcatT, QF, part);
  kv_reduce<<<dim3(32, 9), dim3(256), 0, stream>>>(part, kvr);
  mprep_qn<<<dim3(1536), dim3(256), 0, stream>>>(kvr, Wout, QF, MT, QN);
  gemm_out<<<dim3(4, 256), dim3(256), 0, stream>>>(QN, MT, bout, out);
}